// Round 4
// baseline (801.922 us; speedup 1.0000x reference)
//
#include <hip/hip_runtime.h>
#include <stdint.h>

// GIN forward: B=32, N=1024, D=128, L=2.
// R7: fused mega-kernel with SOFTWARE grid barrier (plain launch, graph-safe).
// R6's cooperative launch silently no-op'd (absmax == max|ref|, out all-zero,
// dur NaN) -> hipLaunchCooperativeKernel rejected by harness capture path.
// Same phase bodies (identical to measured R5 kernels); grid.sync replaced by
// generation-counter barrier in workspace (memset to 0 each launch).
// Co-residency: 512 blocks = 2/CU x 256 CU, __launch_bounds__(256,2),
// LDS 66.6KB <= 80KB/block.

#define BB 32
#define NN 1024
#define DD 128
#define RR 32768  // BB*NN
#define NBLK 512

typedef __bf16 bf16_t;
typedef bf16_t bf16x8 __attribute__((ext_vector_type(8)));
typedef float f32x4 __attribute__((ext_vector_type(4)));

__device__ __forceinline__ unsigned short f2b(float f) {
  unsigned u = __float_as_uint(f);
  u += 0x7fff + ((u >> 16) & 1);  // RNE
  return (unsigned short)(u >> 16);
}
__device__ __forceinline__ float b2f(unsigned short s) {
  return __uint_as_float((unsigned)s << 16);
}

#define GLL(GP, LP)                                              \
  __builtin_amdgcn_global_load_lds(                              \
      (const __attribute__((address_space(1))) void*)(GP),       \
      (__attribute__((address_space(3))) void*)(LP), 16, 0, 0)

// ---- software grid barrier: bar[0]=arrive count, bar[1]=generation ----
__device__ __forceinline__ void gsync(unsigned* bar) {
  __syncthreads();
  if (threadIdx.x == 0) {
    __threadfence();  // release: all prior global writes visible device-wide
    unsigned gen = __hip_atomic_load(bar + 1, __ATOMIC_RELAXED,
                                     __HIP_MEMORY_SCOPE_AGENT);
    unsigned prev = __hip_atomic_fetch_add(bar, 1u, __ATOMIC_ACQ_REL,
                                           __HIP_MEMORY_SCOPE_AGENT);
    if (prev == (unsigned)(NBLK - 1)) {
      __hip_atomic_store(bar, 0u, __ATOMIC_RELAXED, __HIP_MEMORY_SCOPE_AGENT);
      __hip_atomic_fetch_add(bar + 1, 1u, __ATOMIC_RELEASE,
                             __HIP_MEMORY_SCOPE_AGENT);
    } else {
      while (__hip_atomic_load(bar + 1, __ATOMIC_RELAXED,
                               __HIP_MEMORY_SCOPE_AGENT) == gen)
        __builtin_amdgcn_s_sleep(2);
    }
    __threadfence();  // acquire: other blocks' writes visible to this block
  }
  __syncthreads();
}

__global__ __launch_bounds__(256, 2) void k_all(
    const float* __restrict__ x, const float* __restrict__ adj,
    const float* __restrict__ W1, const float* __restrict__ b1,
    const float* __restrict__ W2, const float* __restrict__ b2,
    const float* __restrict__ g_in, const float* __restrict__ be_in,
    const float* __restrict__ g_out, const float* __restrict__ be_out,
    float* __restrict__ out, unsigned short* __restrict__ hT,
    unsigned short* __restrict__ z1b, unsigned short* __restrict__ z2b,
    unsigned short* __restrict__ W1T, unsigned short* __restrict__ W2T,
    float* __restrict__ stats, unsigned* __restrict__ bar) {
  const int blk = blockIdx.x;  // 0..511
  const int tid = threadIdx.x;

  __shared__ union {
    struct {  // phase 0 / phase C transpose
      alignas(16) unsigned short T[128][136];
    } t;
    struct {  // phase A staging (double-buffered)
      float A[2][4096];             // [buf][64 x 64 f32] 16 KB each
      unsigned short Bst[2][8192];  // [buf][128 x 64 bf16] 16 KB each
    } a;
    unsigned short As2[64][136];  // phase A pooled exchange tile
    struct {                      // phase B
      alignas(16) unsigned short Az[64][136];
      alignas(16) unsigned short Ws[128][136];
    } b;
  } sm;
  __shared__ float nsc[128], nsh[128];

  // ================= Phase 0: prep =================
  if (blk < 256) {
    const int b = blk >> 3, nt = blk & 7;
    const int r = tid >> 1, c0 = (tid & 1) * 64;
    const float* src = x + ((size_t)(b * 8 + nt) * 128 + r) * 128 + c0;
#pragma unroll
    for (int i = 0; i < 64; i += 4) {
      float4 v = *(const float4*)(src + i);
      int c = c0 + i;
      sm.t.T[c][r] = f2b(v.x); sm.t.T[c + 1][r] = f2b(v.y);
      sm.t.T[c + 2][r] = f2b(v.z); sm.t.T[c + 3][r] = f2b(v.w);
    }
    __syncthreads();
    const int d = tid >> 1, n0 = (tid & 1) * 64;
    unsigned short* dst = hT + ((size_t)b * DD + d) * NN + nt * 128 + n0;
#pragma unroll
    for (int i = 0; i < 64; i += 8)
      *(uint4*)(dst + i) = *(const uint4*)&sm.t.T[d][n0 + i];
  } else {
    int idx = (blk - 256) * 256 + tid;  // 0..65535
    int w = idx >> 15;
    int rem = idx & 32767;
    int l = rem >> 14;
    int n = (rem >> 7) & 127;
    int k = rem & 127;
    const float* W = w ? W2 : W1;
    unsigned short* WT = w ? W2T : W1T;
    WT[((size_t)l * 128 + n) * 128 + k] = f2b(W[((size_t)l * 128 + k) * 128 + n]);
  }
  gsync(bar);

  for (int l = 0; l < 2; ++l) {
    float* st_in = stats + (l * 2 + 0) * 256;
    float* st_out = stats + (l * 2 + 1) * 256;

    // ================= Phase A: pooled(adj@hT) -> z1 = pooled@W1+b1 + stats
    {
      const int mt = blk & 15, b = blk >> 4;
      const int wave = tid >> 6, lane = tid & 63;
      const int wc = wave * 32;
      const int ln = lane & 15, q = lane >> 4;
      const unsigned short* WTa = W1T + l * 16384;
      const float* biasA = b1 + l * 128;

      // W1 fragments -> registers
      bf16x8 wfr[4][2];
#pragma unroll
      for (int ks = 0; ks < 4; ks++)
#pragma unroll
        for (int j = 0; j < 2; j++)
          wfr[ks][j] = *(const bf16x8*)&WTa[(size_t)(wc + j * 16 + ln) * 128 + ks * 32 + q * 8];
      asm volatile("s_waitcnt vmcnt(0)" ::: "memory");

      // per-thread staging sources (XOR source-swizzle, 16B units)
      const int rA = tid >> 4, uA = tid & 15;
      const float* gAf = adj + ((size_t)b * NN + mt * 64 + rA) * NN + ((uA ^ (rA & 7)) << 2);
      const int rB = tid >> 3, uB = tid & 7;
      const unsigned short* gBs =
          hT + (size_t)b * DD * NN + (size_t)rB * NN + ((uB ^ (rB & 7)) << 3);

#define STAGE(P, K0)                                  \
  do {                                                \
    float* ap = sm.a.A[(P)];                          \
    unsigned short* bp = sm.a.Bst[(P)];               \
    GLL(gAf + (K0), ap + tid * 4);                    \
    GLL(gAf + 16 * NN + (K0), ap + 1024 + tid * 4);   \
    GLL(gAf + 32 * NN + (K0), ap + 2048 + tid * 4);   \
    GLL(gAf + 48 * NN + (K0), ap + 3072 + tid * 4);   \
    GLL(gBs + (K0), bp + tid * 8);                    \
    GLL(gBs + 32 * NN + (K0), bp + 2048 + tid * 8);   \
    GLL(gBs + 64 * NN + (K0), bp + 4096 + tid * 8);   \
    GLL(gBs + 96 * NN + (K0), bp + 6144 + tid * 8);   \
  } while (0)

      STAGE(0, 0);
      STAGE(1, 64);

      f32x4 acc1[4][2];
      f32x4 zero = {0.f, 0.f, 0.f, 0.f};
#pragma unroll
      for (int i = 0; i < 4; i++) { acc1[i][0] = zero; acc1[i][1] = zero; }

      const int x7 = ln & 7;
      const int xorvB = x7 << 4;

#pragma unroll 2
      for (int t = 0; t < 16; ++t) {
        const int p = t & 1;
        if (t < 15)
          asm volatile("s_waitcnt vmcnt(8)" ::: "memory");
        else
          asm volatile("s_waitcnt vmcnt(0)" ::: "memory");
        __builtin_amdgcn_s_barrier();
        __builtin_amdgcn_sched_barrier(0);
        {
          const float* Ab = sm.a.A[p];
          const char* Bb = (const char*)sm.a.Bst[p];
#pragma unroll
          for (int kk = 0; kk < 2; kk++) {
            const int cu = kk * 8 + q * 2;
            bf16x8 af[4], bfr[2];
#pragma unroll
            for (int i = 0; i < 4; i++) {
              const float* arow = Ab + (i * 16 + ln) * 64;
              float4 a0 = *(const float4*)(arow + ((cu ^ x7) << 2));
              float4 a1 = *(const float4*)(arow + (((cu + 1) ^ x7) << 2));
              bf16x8 v;
              v[0] = (bf16_t)a0.x; v[1] = (bf16_t)a0.y;
              v[2] = (bf16_t)a0.z; v[3] = (bf16_t)a0.w;
              v[4] = (bf16_t)a1.x; v[5] = (bf16_t)a1.y;
              v[6] = (bf16_t)a1.z; v[7] = (bf16_t)a1.w;
              af[i] = v;
            }
#pragma unroll
            for (int j = 0; j < 2; j++)
              bfr[j] = *(const bf16x8*)(Bb + (wc + j * 16 + ln) * 128 +
                                        (((kk << 6) + (q << 4)) ^ xorvB));
#pragma unroll
            for (int i = 0; i < 4; i++)
#pragma unroll
              for (int j = 0; j < 2; j++)
                acc1[i][j] = __builtin_amdgcn_mfma_f32_16x16x32_bf16(af[i], bfr[j], acc1[i][j], 0, 0, 0);
          }
        }
        __builtin_amdgcn_sched_barrier(0);
        __builtin_amdgcn_s_barrier();
        __builtin_amdgcn_sched_barrier(0);
        if (t < 14) STAGE(p, (t + 2) * 64);
      }
#undef STAGE

      // pooled tile -> LDS (bf16), A-layout for phase 2
#pragma unroll
      for (int i = 0; i < 4; i++) {
        int row = i * 16 + q * 4;
#pragma unroll
        for (int j = 0; j < 2; j++) {
          int col = wc + j * 16 + ln;
#pragma unroll
          for (int r = 0; r < 4; r++) sm.As2[row + r][col] = f2b(acc1[i][j][r]);
        }
      }
      __syncthreads();

      // z1 = pooled @ W1 (K=128, W in registers)
      f32x4 acc2[4][2];
#pragma unroll
      for (int i = 0; i < 4; i++) { acc2[i][0] = zero; acc2[i][1] = zero; }
#pragma unroll
      for (int ks = 0; ks < 4; ks++) {
        bf16x8 af[4];
#pragma unroll
        for (int i = 0; i < 4; i++)
          af[i] = *(const bf16x8*)&sm.As2[i * 16 + ln][ks * 32 + q * 8];
#pragma unroll
        for (int i = 0; i < 4; i++)
#pragma unroll
          for (int j = 0; j < 2; j++)
            acc2[i][j] = __builtin_amdgcn_mfma_f32_16x16x32_bf16(af[i], wfr[ks][j], acc2[i][j], 0, 0, 0);
      }

      const size_t row0 = (size_t)b * NN + mt * 64;
#pragma unroll
      for (int j = 0; j < 2; j++) {
        int col = wc + j * 16 + ln;
        float bc = biasA[col];
        float s1 = 0.f, s2 = 0.f;
#pragma unroll
        for (int i = 0; i < 4; i++) {
          int row = i * 16 + q * 4;
#pragma unroll
          for (int r = 0; r < 4; r++) {
            float v = acc2[i][j][r] + bc;
            z1b[(row0 + row + r) * 128 + col] = f2b(v);
            s1 += v; s2 += v * v;
          }
        }
        s1 += __shfl_xor(s1, 16); s1 += __shfl_xor(s1, 32);
        s2 += __shfl_xor(s2, 16); s2 += __shfl_xor(s2, 32);
        if (q == 0) { atomicAdd(&st_in[col], s1); atomicAdd(&st_in[128 + col], s2); }
      }
    }
    gsync(bar);

    // ================= Phase B: z2 = relu(BN(z1)) @ W2 + b2 + stats =========
    {
      const int mt = blk;
      const int wave = tid >> 6, lane = tid & 63;
      const int wc = wave * 32;
      const int ln = lane & 15, q = lane >> 4;
      const unsigned short* WTb = W2T + l * 16384;
      const float* biasB = b2 + l * 128;
      const float* gam = g_in + l * 128;
      const float* bet = be_in + l * 128;

      if (tid < 128) {
        float mean = st_in[tid] * (1.f / 32768.f);
        float var = st_in[128 + tid] * (1.f / 32768.f) - mean * mean;
        float sc = gam[tid] * rsqrtf(var + 1e-5f);
        nsc[tid] = sc; nsh[tid] = bet[tid] - mean * sc;
      }
#pragma unroll
      for (int p = 0; p < 8; p++) {
        int c = tid + p * 256;
        int n = c >> 4, k8 = (c & 15) * 8;
        *(uint4*)&sm.b.Ws[n][k8] = *(const uint4*)&WTb[n * 128 + k8];
      }
      __syncthreads();

      const size_t row0 = (size_t)mt * 64;
      {
        const int r = tid >> 2, c0 = (tid & 3) * 32;
        const unsigned short* src = z1b + (row0 + r) * 128 + c0;
#pragma unroll
        for (int u = 0; u < 4; u++) {
          uint4 raw = *(const uint4*)(src + u * 8);
          const unsigned short* s = (const unsigned short*)&raw;
          alignas(16) unsigned short tmp[8];
#pragma unroll
          for (int e = 0; e < 8; e++) {
            int c = c0 + u * 8 + e;
            tmp[e] = f2b(fmaxf(fmaf(b2f(s[e]), nsc[c], nsh[c]), 0.f));
          }
          *(uint4*)&sm.b.Az[r][c0 + u * 8] = *(const uint4*)&tmp[0];
        }
      }
      __syncthreads();

      f32x4 acc[4][2];
      f32x4 zero = {0.f, 0.f, 0.f, 0.f};
#pragma unroll
      for (int i = 0; i < 4; i++) { acc[i][0] = zero; acc[i][1] = zero; }
#pragma unroll
      for (int ks = 0; ks < 4; ks++) {
        bf16x8 af[4], bfr[2];
#pragma unroll
        for (int i = 0; i < 4; i++)
          af[i] = *(const bf16x8*)&sm.b.Az[i * 16 + ln][ks * 32 + q * 8];
#pragma unroll
        for (int j = 0; j < 2; j++)
          bfr[j] = *(const bf16x8*)&sm.b.Ws[wc + j * 16 + ln][ks * 32 + q * 8];
#pragma unroll
        for (int i = 0; i < 4; i++)
#pragma unroll
          for (int j = 0; j < 2; j++)
            acc[i][j] = __builtin_amdgcn_mfma_f32_16x16x32_bf16(af[i], bfr[j], acc[i][j], 0, 0, 0);
      }

#pragma unroll
      for (int j = 0; j < 2; j++) {
        int col = wc + j * 16 + ln;
        float bc = biasB[col];
        float s1 = 0.f, s2 = 0.f;
#pragma unroll
        for (int i = 0; i < 4; i++) {
          int row = i * 16 + q * 4;
#pragma unroll
          for (int r = 0; r < 4; r++) {
            float v = acc[i][j][r] + bc;
            z2b[(row0 + row + r) * 128 + col] = f2b(v);
            s1 += v; s2 += v * v;
          }
        }
        s1 += __shfl_xor(s1, 16); s1 += __shfl_xor(s1, 32);
        s2 += __shfl_xor(s2, 16); s2 += __shfl_xor(s2, 32);
        if (q == 0) { atomicAdd(&st_out[col], s1); atomicAdd(&st_out[128 + col], s2); }
      }
    }
    gsync(bar);

    // ================= Phase C: h = relu(BN(z2)) =================
    if (l == 0) {
      // -> hT bf16 [b][d][n] via LDS transpose; block = 64-row strip
      const int b = blk >> 4, nseg = blk & 15;
      if (tid < 128) {
        float mean = st_out[tid] * (1.f / 32768.f);
        float var = st_out[128 + tid] * (1.f / 32768.f) - mean * mean;
        float sc = g_out[tid] * rsqrtf(var + 1e-5f);
        nsc[tid] = sc; nsh[tid] = be_out[tid] - mean * sc;
      }
      __syncthreads();
      const size_t zrow0 = (size_t)b * NN + nseg * 64;
      {
        const int r = tid >> 2, c0 = (tid & 3) * 32;
        const unsigned short* src = z2b + (zrow0 + r) * 128 + c0;
#pragma unroll
        for (int u = 0; u < 4; u++) {
          uint4 raw = *(const uint4*)(src + u * 8);
          const unsigned short* s = (const unsigned short*)&raw;
#pragma unroll
          for (int e = 0; e < 8; e++) {
            int c = c0 + u * 8 + e;
            sm.t.T[c][r] = f2b(fmaxf(fmaf(b2f(s[e]), nsc[c], nsh[c]), 0.f));
          }
        }
      }
      __syncthreads();
      const int d = tid >> 1, nh = (tid & 1) * 32;
      unsigned short* dst = hT + ((size_t)b * DD + d) * NN + nseg * 64 + nh;
#pragma unroll
      for (int i = 0; i < 32; i += 8)
        *(uint4*)(dst + i) = *(const uint4*)&sm.t.T[d][nh + i];
      gsync(bar);
    } else {
      // final: -> out f32 [b][n][d]
      if (tid < 128) {
        float mean = st_out[tid] * (1.f / 32768.f);
        float var = st_out[128 + tid] * (1.f / 32768.f) - mean * mean;
        float sc = g_out[128 + tid] * rsqrtf(var + 1e-5f);
        nsc[tid] = sc; nsh[tid] = be_out[128 + tid] - mean * sc;
      }
      __syncthreads();
      const size_t row0 = (size_t)blk * 64;
      const int r = tid >> 2, c0 = (tid & 3) * 32;
      const unsigned short* src = z2b + (row0 + r) * 128 + c0;
      float* dst = out + (row0 + r) * 128 + c0;
#pragma unroll
      for (int u = 0; u < 4; u++) {
        uint4 raw = *(const uint4*)(src + u * 8);
        const unsigned short* s = (const unsigned short*)&raw;
        float4 o;
        int c = c0 + u * 8;
        o.x = fmaxf(fmaf(b2f(s[0]), nsc[c], nsh[c]), 0.f);
        o.y = fmaxf(fmaf(b2f(s[1]), nsc[c + 1], nsh[c + 1]), 0.f);
        o.z = fmaxf(fmaf(b2f(s[2]), nsc[c + 2], nsh[c + 2]), 0.f);
        o.w = fmaxf(fmaf(b2f(s[3]), nsc[c + 3], nsh[c + 3]), 0.f);
        *(float4*)(dst + u * 8) = o;
        o.x = fmaxf(fmaf(b2f(s[4]), nsc[c + 4], nsh[c + 4]), 0.f);
        o.y = fmaxf(fmaf(b2f(s[5]), nsc[c + 5], nsh[c + 5]), 0.f);
        o.z = fmaxf(fmaf(b2f(s[6]), nsc[c + 6], nsh[c + 6]), 0.f);
        o.w = fmaxf(fmaf(b2f(s[7]), nsc[c + 7], nsh[c + 7]), 0.f);
        *(float4*)(dst + u * 8 + 4) = o;
      }
    }
  }
}

extern "C" void kernel_launch(void* const* d_in, const int* in_sizes, int n_in,
                              void* d_out, int out_size, void* d_ws, size_t ws_size,
                              hipStream_t stream) {
  const float* x = (const float*)d_in[0];
  const float* adj = (const float*)d_in[2];
  const float* W1 = (const float*)d_in[3];
  const float* b1 = (const float*)d_in[4];
  const float* W2 = (const float*)d_in[5];
  const float* b2 = (const float*)d_in[6];
  const float* g_in = (const float*)d_in[7];
  const float* be_in = (const float*)d_in[8];
  const float* g_out = (const float*)d_in[9];
  const float* be_out = (const float*)d_in[10];
  float* out = (float*)d_out;

  char* ws = (char*)d_ws;
  unsigned short* hT = (unsigned short*)ws;                           // 8 MB
  unsigned short* z1b = (unsigned short*)(ws + 8ull * 1024 * 1024);   // 8 MB
  unsigned short* z2b = (unsigned short*)(ws + 16ull * 1024 * 1024);  // 8 MB
  unsigned short* W1T = (unsigned short*)(ws + 24ull * 1024 * 1024);  // 64 KB
  unsigned short* W2T = W1T + 2 * 128 * 128;                          // 64 KB
  float* stats = (float*)(ws + 25ull * 1024 * 1024);                  // 4 x 256 f32
  unsigned* bar = (unsigned*)(stats + 4 * 256);                       // 2 u32

  // zero stats + barrier state (workspace is re-poisoned between iterations)
  hipMemsetAsync(stats, 0, 4 * 256 * sizeof(float) + 64, stream);
  k_all<<<NBLK, 256, 0, stream>>>(x, adj, W1, b1, W2, b2, g_in, be_in, g_out,
                                  be_out, out, hT, z1b, z2b, W1T, W2T, stats,
                                  bar);
}

// Round 5
// 350.774 us; speedup vs baseline: 2.2861x; 2.2861x over previous
//
#include <hip/hip_runtime.h>
#include <stdint.h>

// GIN forward: B=32, N=1024, D=128, L=2.
// R8: back to multi-kernel (fused+SW-barrier = 664us, barrier ~50us/sync).
//  - k0: + adj f32->bf16 (poison fill proven constant-cost: 512MB regardless).
//  - kA: depth-3 global_load_lds pipeline (bf16 adj, 6 GLL/tile, vmcnt(12)),
//        72KB LDS triple-buffer, 2 blocks/CU.
//  - kB: W2 frags in regs, raw-z1 GLL staging, BN+ReLU fused into the
//        LDS->fragment read path; single barrier.
//  - k4t/k4e unchanged.

#define BB 32
#define NN 1024
#define DD 128
#define RR 32768  // BB*NN

typedef __bf16 bf16_t;
typedef bf16_t bf16x8 __attribute__((ext_vector_type(8)));
typedef unsigned short us8 __attribute__((ext_vector_type(8)));
typedef float f32x4 __attribute__((ext_vector_type(4)));

__device__ __forceinline__ unsigned short f2b(float f) {
  unsigned u = __float_as_uint(f);
  u += 0x7fff + ((u >> 16) & 1);  // RNE
  return (unsigned short)(u >> 16);
}
__device__ __forceinline__ float b2f(unsigned short s) {
  return __uint_as_float((unsigned)s << 16);
}

#define GLL(GP, LP)                                              \
  __builtin_amdgcn_global_load_lds(                              \
      (const __attribute__((address_space(1))) void*)(GP),       \
      (__attribute__((address_space(3))) void*)(LP), 16, 0, 0)

// ---------------- K0: x->hT (0..255), W->WT (256..511), adj->bf16 (512..) ---
__global__ __launch_bounds__(256) void k0_prep(const float* __restrict__ x,
                                               const float* __restrict__ adj,
                                               const float* __restrict__ W1,
                                               const float* __restrict__ W2,
                                               unsigned short* __restrict__ hT,
                                               unsigned short* __restrict__ W1T,
                                               unsigned short* __restrict__ W2T,
                                               unsigned short* __restrict__ adjB) {
  const int tid = threadIdx.x;
  if (blockIdx.x >= 512) {
    size_t i8 = ((size_t)(blockIdx.x - 512) * 256 + tid) * 8;
    float4 a = *(const float4*)(adj + i8);
    float4 b = *(const float4*)(adj + i8 + 4);
    alignas(16) unsigned short t[8] = {f2b(a.x), f2b(a.y), f2b(a.z), f2b(a.w),
                                       f2b(b.x), f2b(b.y), f2b(b.z), f2b(b.w)};
    *(uint4*)(adjB + i8) = *(const uint4*)t;
    return;
  }
  if (blockIdx.x < 256) {
    const int b = blockIdx.x >> 3, nt = blockIdx.x & 7;
    __shared__ alignas(16) unsigned short T[128][136];
    const int r = tid >> 1, c0 = (tid & 1) * 64;
    const float* src = x + ((size_t)(b * 8 + nt) * 128 + r) * 128 + c0;
#pragma unroll
    for (int i = 0; i < 64; i += 4) {
      float4 v = *(const float4*)(src + i);
      int c = c0 + i;
      T[c][r] = f2b(v.x); T[c + 1][r] = f2b(v.y);
      T[c + 2][r] = f2b(v.z); T[c + 3][r] = f2b(v.w);
    }
    __syncthreads();
    const int d = tid >> 1, n0 = (tid & 1) * 64;
    unsigned short* dst = hT + ((size_t)b * DD + d) * NN + nt * 128 + n0;
#pragma unroll
    for (int i = 0; i < 64; i += 8)
      *(uint4*)(dst + i) = *(const uint4*)&T[d][n0 + i];
  } else {
    int idx = (blockIdx.x - 256) * 256 + tid;  // 0..65535
    int w = idx >> 15;
    int rem = idx & 32767;
    int l = rem >> 14;
    int n = (rem >> 7) & 127;
    int k = rem & 127;
    const float* W = w ? W2 : W1;
    unsigned short* WT = w ? W2T : W1T;
    WT[((size_t)l * 128 + n) * 128 + k] = f2b(W[((size_t)l * 128 + k) * 128 + n]);
  }
}

// ---------------- kA: pooled (adjB@hT) fused with z1 = pooled@W1 + b1 + stats
// 64 adj-rows x 128 d per block; depth-3 GLL pipeline, BK=64, vmcnt(12).
__global__ __launch_bounds__(256, 2) void kA_pool_lin(
    const unsigned short* __restrict__ adjB, const unsigned short* __restrict__ hT,
    const unsigned short* __restrict__ WT, const float* __restrict__ bias,
    unsigned short* __restrict__ z1b, float* __restrict__ gsum,
    float* __restrict__ gsq) {
  const int mt = blockIdx.x, b = blockIdx.y;
  const int tid = threadIdx.x;
  const int wave = tid >> 6, lane = tid & 63;
  const int wc = wave * 32;
  const int ln = lane & 15, q = lane >> 4;

  __shared__ union {
    struct {
      unsigned short A[3][4096];  // [buf][64 x 64 bf16]  8 KB each
      unsigned short B[3][8192];  // [buf][128 x 64 bf16] 16 KB each
    } s;
    unsigned short As2[64][136];  // pooled exchange tile (phase 2 A)
  } sm;

  // W1 fragments -> registers
  bf16x8 wfr[4][2];
#pragma unroll
  for (int ks = 0; ks < 4; ks++)
#pragma unroll
    for (int j = 0; j < 2; j++)
      wfr[ks][j] = *(const bf16x8*)&WT[(size_t)(wc + j * 16 + ln) * 128 + ks * 32 + q * 8];
  asm volatile("s_waitcnt vmcnt(0)" ::: "memory");  // W loads out of vmcnt stream

  const unsigned short* adjb = adjB + ((size_t)b * NN + mt * 64) * NN;
  const unsigned short* hTb = hT + (size_t)b * DD * NN;

  // per-thread staging source (XOR source-swizzle within 8x16B tile row)
  const int srow = tid >> 3;                         // 0..31
  const int sseg = (((tid & 7) ^ (srow & 7)) << 3);  // shorts
  const unsigned short* gA = adjb + (size_t)srow * NN + sseg;  // rows srow,+32
  const unsigned short* gB = hTb + (size_t)srow * NN + sseg;   // rows +0,32,64,96

#define STAGE(P, K0)                                \
  do {                                              \
    unsigned short* ap = sm.s.A[(P)];               \
    unsigned short* bp = sm.s.B[(P)];               \
    GLL(gA + (K0), ap + tid * 8);                   \
    GLL(gA + 32 * NN + (K0), ap + 2048 + tid * 8);  \
    GLL(gB + (K0), bp + tid * 8);                   \
    GLL(gB + 32 * NN + (K0), bp + 2048 + tid * 8);  \
    GLL(gB + 64 * NN + (K0), bp + 4096 + tid * 8);  \
    GLL(gB + 96 * NN + (K0), bp + 6144 + tid * 8);  \
  } while (0)

  STAGE(0, 0);
  STAGE(1, 64);
  STAGE(2, 128);

  f32x4 acc1[4][2];
  f32x4 zero = {0.f, 0.f, 0.f, 0.f};
#pragma unroll
  for (int i = 0; i < 4; i++) { acc1[i][0] = zero; acc1[i][1] = zero; }

  const int xorv = (ln & 7) << 4;  // byte XOR on read side (same involution)

#pragma unroll
  for (int t = 0; t < 16; ++t) {
    const int p = t % 3;
    if (t < 14)
      asm volatile("s_waitcnt vmcnt(12)" ::: "memory");  // tile t landed, t+1/t+2 in flight
    else if (t == 14)
      asm volatile("s_waitcnt vmcnt(6)" ::: "memory");
    else
      asm volatile("s_waitcnt vmcnt(0)" ::: "memory");
    __builtin_amdgcn_s_barrier();
    __builtin_amdgcn_sched_barrier(0);
    {
      const char* Ab = (const char*)sm.s.A[p];
      const char* Bb = (const char*)sm.s.B[p];
#pragma unroll
      for (int kk = 0; kk < 2; kk++) {
        const int co = ((kk << 6) + (q << 4)) ^ xorv;
        bf16x8 af[4], bfr[2];
#pragma unroll
        for (int i = 0; i < 4; i++)
          af[i] = *(const bf16x8*)(Ab + (i * 16 + ln) * 128 + co);
#pragma unroll
        for (int j = 0; j < 2; j++)
          bfr[j] = *(const bf16x8*)(Bb + (wc + j * 16 + ln) * 128 + co);
#pragma unroll
        for (int i = 0; i < 4; i++)
#pragma unroll
          for (int j = 0; j < 2; j++)
            acc1[i][j] = __builtin_amdgcn_mfma_f32_16x16x32_bf16(af[i], bfr[j], acc1[i][j], 0, 0, 0);
      }
    }
    __builtin_amdgcn_sched_barrier(0);
    __builtin_amdgcn_s_barrier();  // all waves done reading buf p
    __builtin_amdgcn_sched_barrier(0);
    if (t < 13) STAGE(p, (t + 3) * 64);
  }
#undef STAGE

  // pooled tile -> LDS (bf16), A-layout for phase 2 (overwrites stage area)
#pragma unroll
  for (int i = 0; i < 4; i++) {
    int row = i * 16 + q * 4;
#pragma unroll
    for (int j = 0; j < 2; j++) {
      int col = wc + j * 16 + ln;
#pragma unroll
      for (int r = 0; r < 4; r++) sm.As2[row + r][col] = f2b(acc1[i][j][r]);
    }
  }
  __syncthreads();

  // phase 2: z1 = pooled @ W1 (K=128, W in registers, no barriers)
  f32x4 acc2[4][2];
#pragma unroll
  for (int i = 0; i < 4; i++) { acc2[i][0] = zero; acc2[i][1] = zero; }
#pragma unroll
  for (int ks = 0; ks < 4; ks++) {
    bf16x8 af[4];
#pragma unroll
    for (int i = 0; i < 4; i++)
      af[i] = *(const bf16x8*)&sm.As2[i * 16 + ln][ks * 32 + q * 8];
#pragma unroll
    for (int i = 0; i < 4; i++)
#pragma unroll
      for (int j = 0; j < 2; j++)
        acc2[i][j] = __builtin_amdgcn_mfma_f32_16x16x32_bf16(af[i], wfr[ks][j], acc2[i][j], 0, 0, 0);
  }

  // epilogue: +bias, write z1 bf16, column stats (cols unique per wave)
  const size_t row0 = (size_t)b * NN + mt * 64;
#pragma unroll
  for (int j = 0; j < 2; j++) {
    int col = wc + j * 16 + ln;
    float bc = bias[col];
    float s1 = 0.f, s2 = 0.f;
#pragma unroll
    for (int i = 0; i < 4; i++) {
      int row = i * 16 + q * 4;
#pragma unroll
      for (int r = 0; r < 4; r++) {
        float v = acc2[i][j][r] + bc;
        z1b[(row0 + row + r) * 128 + col] = f2b(v);
        s1 += v; s2 += v * v;
      }
    }
    s1 += __shfl_xor(s1, 16); s1 += __shfl_xor(s1, 32);
    s2 += __shfl_xor(s2, 16); s2 += __shfl_xor(s2, 32);
    if (q == 0) { atomicAdd(&gsum[col], s1); atomicAdd(&gsq[col], s2); }
  }
}

// ---------------- kB: z2 = relu(BN(z1)) @ W2 + b2 + stats ----------------
// W frags in regs; raw z1 via GLL (swizzled src); BN fused into frag read.
__global__ __launch_bounds__(256, 2) void kB_lin(
    const unsigned short* __restrict__ Zin, const float* __restrict__ gsum_in,
    const float* __restrict__ gsq_in, const float* __restrict__ gamma,
    const float* __restrict__ beta, const unsigned short* __restrict__ WT,
    const float* __restrict__ bias, unsigned short* __restrict__ z2b,
    float* __restrict__ gsum, float* __restrict__ gsq) {
  const int mt = blockIdx.x;
  const int tid = threadIdx.x;
  const int wave = tid >> 6, lane = tid & 63;
  const int wc = wave * 32;
  const int ln = lane & 15, q = lane >> 4;

  __shared__ alignas(16) unsigned short Az[64 * 128];  // raw z1, 16 KB
  __shared__ float nsc[128], nsh[128];

  // W2 fragments -> registers
  bf16x8 wfr[4][2];
#pragma unroll
  for (int ks = 0; ks < 4; ks++)
#pragma unroll
    for (int j = 0; j < 2; j++)
      wfr[ks][j] = *(const bf16x8*)&WT[(size_t)(wc + j * 16 + ln) * 128 + ks * 32 + q * 8];

  // stage raw z1 tile 64x128 via GLL, source-swizzled (rows 256B = 16 units)
  const size_t row0 = (size_t)mt * 64;
  const int rZ = tid >> 4;                            // 0..15
  const int uZ = (((tid & 15) ^ (rZ & 7)) << 3);      // shorts
  const unsigned short* gZ = Zin + (row0 + rZ) * 128 + uZ;
  GLL(gZ, Az + tid * 8);
  GLL(gZ + 16 * 128, Az + 2048 + tid * 8);
  GLL(gZ + 32 * 128, Az + 4096 + tid * 8);
  GLL(gZ + 48 * 128, Az + 6144 + tid * 8);

  if (tid < 128) {
    float mean = gsum_in[tid] * (1.f / 32768.f);
    float var = gsq_in[tid] * (1.f / 32768.f) - mean * mean;
    float sc = gamma[tid] * rsqrtf(var + 1e-5f);
    nsc[tid] = sc; nsh[tid] = beta[tid] - mean * sc;
  }
  __syncthreads();  // GLL landed (vmcnt0 implied) + nsc/nsh ready

  f32x4 acc[4][2];
  f32x4 zero = {0.f, 0.f, 0.f, 0.f};
#pragma unroll
  for (int i = 0; i < 4; i++) { acc[i][0] = zero; acc[i][1] = zero; }

  const int xorv = (ln & 7) << 4;
#pragma unroll
  for (int ks = 0; ks < 4; ks++) {
    bf16x8 af[4];
#pragma unroll
    for (int i = 0; i < 4; i++) {
      us8 raw = *(const us8*)((const char*)Az + (i * 16 + ln) * 256 +
                              (((ks << 6) + (q << 4)) ^ xorv));
      us8 t;
#pragma unroll
      for (int e = 0; e < 8; e++) {
        int col = ks * 32 + q * 8 + e;
        t[e] = f2b(fmaxf(fmaf(b2f(raw[e]), nsc[col], nsh[col]), 0.f));
      }
      af[i] = *(bf16x8*)&t;
    }
#pragma unroll
    for (int i = 0; i < 4; i++)
#pragma unroll
      for (int j = 0; j < 2; j++)
        acc[i][j] = __builtin_amdgcn_mfma_f32_16x16x32_bf16(af[i], wfr[ks][j], acc[i][j], 0, 0, 0);
  }

#pragma unroll
  for (int j = 0; j < 2; j++) {
    int col = wc + j * 16 + ln;
    float bc = bias[col];
    float s1 = 0.f, s2 = 0.f;
#pragma unroll
    for (int i = 0; i < 4; i++) {
      int row = i * 16 + q * 4;
#pragma unroll
      for (int r = 0; r < 4; r++) {
        float v = acc[i][j][r] + bc;
        z2b[(row0 + row + r) * 128 + col] = f2b(v);
        s1 += v; s2 += v * v;
      }
    }
    s1 += __shfl_xor(s1, 16); s1 += __shfl_xor(s1, 32);
    s2 += __shfl_xor(s2, 16); s2 += __shfl_xor(s2, 32);
    if (q == 0) { atomicAdd(&gsum[col], s1); atomicAdd(&gsq[col], s2); }
  }
}

// -------- K4t: h = relu(BN(z2)) -> hT bf16 [b][d][n] (LDS transpose) --------
__global__ __launch_bounds__(256) void k4_bnt(const unsigned short* __restrict__ Z,
                                              const float* __restrict__ gsum,
                                              const float* __restrict__ gsq,
                                              const float* __restrict__ gamma,
                                              const float* __restrict__ beta,
                                              unsigned short* __restrict__ hT) {
  const int b = blockIdx.x, nt = blockIdx.y, tid = threadIdx.x;
  __shared__ alignas(16) unsigned short T[128][136];
  __shared__ float nsc[128], nsh[128];
  if (tid < 128) {
    float mean = gsum[tid] * (1.f / 32768.f);
    float var = gsq[tid] * (1.f / 32768.f) - mean * mean;
    float sc = gamma[tid] * rsqrtf(var + 1e-5f);
    nsc[tid] = sc; nsh[tid] = beta[tid] - mean * sc;
  }
  __syncthreads();
  const int r = tid >> 1, c0 = (tid & 1) * 64;
  const unsigned short* src = Z + ((size_t)(b * 8 + nt) * 128 + r) * 128 + c0;
#pragma unroll
  for (int u = 0; u < 8; u++) {
    uint4 raw = *(const uint4*)(src + u * 8);
    const unsigned short* s = (const unsigned short*)&raw;
#pragma unroll
    for (int e = 0; e < 8; e++) {
      int c = c0 + u * 8 + e;
      T[c][r] = f2b(fmaxf(fmaf(b2f(s[e]), nsc[c], nsh[c]), 0.f));
    }
  }
  __syncthreads();
  const int d = tid >> 1, n0 = (tid & 1) * 64;
  unsigned short* dst = hT + ((size_t)b * DD + d) * NN + nt * 128 + n0;
#pragma unroll
  for (int i = 0; i < 64; i += 8)
    *(uint4*)(dst + i) = *(const uint4*)&T[d][n0 + i];
}

// -------- K4e: final h = relu(BN(z2)) -> d_out f32 [b][n][d] --------
__global__ __launch_bounds__(256) void k4_out(const unsigned short* __restrict__ Z,
                                              const float* __restrict__ gsum,
                                              const float* __restrict__ gsq,
                                              const float* __restrict__ gamma,
                                              const float* __restrict__ beta,
                                              float* __restrict__ out) {
  const int blk = blockIdx.x, tid = threadIdx.x;
  __shared__ float nsc[128], nsh[128];
  if (tid < 128) {
    float mean = gsum[tid] * (1.f / 32768.f);
    float var = gsq[tid] * (1.f / 32768.f) - mean * mean;
    float sc = gamma[tid] * rsqrtf(var + 1e-5f);
    nsc[tid] = sc; nsh[tid] = beta[tid] - mean * sc;
  }
  __syncthreads();
  const int r = tid >> 1, c0 = (tid & 1) * 64;
  const unsigned short* src = Z + ((size_t)blk * 128 + r) * 128 + c0;
  float* dst = out + ((size_t)blk * 128 + r) * 128 + c0;
#pragma unroll
  for (int u = 0; u < 8; u++) {
    uint4 raw = *(const uint4*)(src + u * 8);
    const unsigned short* s = (const unsigned short*)&raw;
    float4 o;
    int c = c0 + u * 8;
    o.x = fmaxf(fmaf(b2f(s[0]), nsc[c], nsh[c]), 0.f);
    o.y = fmaxf(fmaf(b2f(s[1]), nsc[c + 1], nsh[c + 1]), 0.f);
    o.z = fmaxf(fmaf(b2f(s[2]), nsc[c + 2], nsh[c + 2]), 0.f);
    o.w = fmaxf(fmaf(b2f(s[3]), nsc[c + 3], nsh[c + 3]), 0.f);
    *(float4*)(dst + u * 8) = o;
    o.x = fmaxf(fmaf(b2f(s[4]), nsc[c + 4], nsh[c + 4]), 0.f);
    o.y = fmaxf(fmaf(b2f(s[5]), nsc[c + 5], nsh[c + 5]), 0.f);
    o.z = fmaxf(fmaf(b2f(s[6]), nsc[c + 6], nsh[c + 6]), 0.f);
    o.w = fmaxf(fmaf(b2f(s[7]), nsc[c + 7], nsh[c + 7]), 0.f);
    *(float4*)(dst + u * 8 + 4) = o;
  }
}

extern "C" void kernel_launch(void* const* d_in, const int* in_sizes, int n_in,
                              void* d_out, int out_size, void* d_ws, size_t ws_size,
                              hipStream_t stream) {
  const float* x = (const float*)d_in[0];
  const float* adj = (const float*)d_in[2];
  const float* W1 = (const float*)d_in[3];
  const float* b1 = (const float*)d_in[4];
  const float* W2 = (const float*)d_in[5];
  const float* b2 = (const float*)d_in[6];
  const float* g_in = (const float*)d_in[7];
  const float* be_in = (const float*)d_in[8];
  const float* g_out = (const float*)d_in[9];
  const float* be_out = (const float*)d_in[10];
  float* out = (float*)d_out;

  char* ws = (char*)d_ws;
  unsigned short* hT = (unsigned short*)ws;                           // 8 MB
  unsigned short* z1b = (unsigned short*)(ws + 8ull * 1024 * 1024);   // 8 MB
  unsigned short* z2b = (unsigned short*)(ws + 16ull * 1024 * 1024);  // 8 MB
  unsigned short* W1T = (unsigned short*)(ws + 24ull * 1024 * 1024);  // 64 KB
  unsigned short* W2T = W1T + 2 * 128 * 128;                          // 64 KB
  float* stats = (float*)(ws + 25ull * 1024 * 1024);                  // 4 x 256 f32
  unsigned short* adjB = (unsigned short*)(ws + 26ull * 1024 * 1024); // 64 MB

  hipMemsetAsync(stats, 0, 4 * 256 * sizeof(float), stream);
  k0_prep<<<512 + 16384, 256, 0, stream>>>(x, adj, W1, W2, hT, W1T, W2T, adjB);

  for (int l = 0; l < 2; l++) {
    float* st_in = stats + (l * 2 + 0) * 256;
    float* st_out = stats + (l * 2 + 1) * 256;
    kA_pool_lin<<<dim3(16, 32), 256, 0, stream>>>(adjB, hT, W1T + l * 16384,
                                                  b1 + l * 128, z1b, st_in,
                                                  st_in + 128);
    kB_lin<<<512, 256, 0, stream>>>(z1b, st_in, st_in + 128, g_in + l * 128,
                                    be_in + l * 128, W2T + l * 16384,
                                    b2 + l * 128, z2b, st_out, st_out + 128);
    if (l == 0)
      k4_bnt<<<dim3(32, 8), 256, 0, stream>>>(z2b, st_out, st_out + 128, g_out,
                                              be_out, hT);
    else
      k4_out<<<256, 256, 0, stream>>>(z2b, st_out, st_out + 128, g_out + 128,
                                      be_out + 128, out);
  }
}